// Round 2
// baseline (1784.529 us; speedup 1.0000x reference)
//
#include <hip/hip_runtime.h>
#include <hip/hip_bf16.h>

// Problem constants (from reference setup_inputs)
#define CN0   100000
#define CN1   200000
#define CNNZ  400000
#define CD    256

typedef __attribute__((ext_vector_type(8))) short bfrag8;   // 8 bf16 (4 VGPRs) — MFMA A/B frag
typedef __attribute__((ext_vector_type(4))) float f32x4v;   // MFMA C/D frag

static __device__ __forceinline__ float b2f(unsigned short u) {
    union { unsigned int i; float f; } c; c.i = ((unsigned int)u) << 16; return c.f;
}
static __device__ __forceinline__ unsigned short f2b(float f) {
    union { float f; unsigned int i; } c; c.f = f;
    unsigned int u = c.i;
    unsigned int r = u + 0x7FFFu + ((u >> 16) & 1u);  // round-to-nearest-even
    return (unsigned short)(r >> 16);
}

// ---------------------------------------------------------------------------
// Kernel 0: transpose+convert W fp32 [K=256][N=256] -> Wt bf16 [N][K] so
// B-fragments are contiguous 16B per lane. Tiny (256 KB read), runs once.
// ---------------------------------------------------------------------------
__global__ __launch_bounds__(256) void transpose_w(const float* __restrict__ w,
                                                   unsigned short* __restrict__ wt) {
    int n = blockIdx.x;   // 0..255
    int k = threadIdx.x;  // 0..255
    wt[n * CD + k] = f2b(w[k * CD + n]);
}

// ---------------------------------------------------------------------------
// Kernel 1: msg[M=100000][256] = bf16(x0) @ bf16(W)  (fp32 accum, bf16 out)
// One wave computes a 16-row x 256-col strip. mfma_f32_16x16x32_bf16:
//   A frag: lane holds A[m=lane&15][k = (lane>>4)*8 + j], j=0..7
//   B frag: lane holds B[k = (lane>>4)*8 + j][n=lane&15] -> from Wt, 16B contig
//   C/D:    col = lane&15, row = (lane>>4)*4 + reg
// ---------------------------------------------------------------------------
__global__ __launch_bounds__(256) void gemm_kernel(const float* __restrict__ x0,
                                                   const unsigned short* __restrict__ wt,
                                                   unsigned short* __restrict__ msg) {
    const int wave = threadIdx.x >> 6;
    const int lane = threadIdx.x & 63;
    const int tile = blockIdx.x * 4 + wave;   // 16-row tile index
    const int m0 = tile * 16;
    if (m0 >= CN0) return;

    const int r16  = lane & 15;
    const int quad = lane >> 4;

    const float* arow = x0 + (size_t)(m0 + r16) * CD + (quad << 3);

    f32x4v acc[16];
#pragma unroll
    for (int i = 0; i < 16; ++i) acc[i] = (f32x4v){0.f, 0.f, 0.f, 0.f};

    for (int k0 = 0; k0 < CD; k0 += 32) {
        float4 a0 = *(const float4*)(arow + k0);
        float4 a1 = *(const float4*)(arow + k0 + 4);
        bfrag8 a;
        a[0] = (short)f2b(a0.x); a[1] = (short)f2b(a0.y);
        a[2] = (short)f2b(a0.z); a[3] = (short)f2b(a0.w);
        a[4] = (short)f2b(a1.x); a[5] = (short)f2b(a1.y);
        a[6] = (short)f2b(a1.z); a[7] = (short)f2b(a1.w);
#pragma unroll
        for (int nt = 0; nt < 16; ++nt) {
            bfrag8 b = *(const bfrag8*)(wt + (size_t)((nt << 4) + r16) * CD + (quad << 3) + k0);
            acc[nt] = __builtin_amdgcn_mfma_f32_16x16x32_bf16(a, b, acc[nt], 0, 0, 0);
        }
    }

    const int mrow = m0 + (quad << 2);
#pragma unroll
    for (int nt = 0; nt < 16; ++nt) {
#pragma unroll
        for (int r = 0; r < 4; ++r) {
            msg[(size_t)(mrow + r) * CD + (nt << 4) + r16] = f2b(acc[nt][r]);
        }
    }
}

// ---------------------------------------------------------------------------
// Kernel 2: scatter-add. One 64-lane wave per edge; each lane handles 4 cols.
// agg[row][c] += val * msg[col][c]   (fp32 HW atomics, avg 2 edges/row)
// ---------------------------------------------------------------------------
__global__ __launch_bounds__(256) void scatter_kernel(const unsigned short* __restrict__ msg,
                                                      const int* __restrict__ rows,
                                                      const int* __restrict__ cols,
                                                      const float* __restrict__ vals,
                                                      float* __restrict__ agg) {
    const int e = blockIdx.x * 4 + (threadIdx.x >> 6);
    if (e >= CNNZ) return;
    const int lane = threadIdx.x & 63;

    const int col = cols[e];
    const int row = rows[e];
    const float v = vals[e];

    const ushort4 m4 = *(const ushort4*)(msg + (size_t)col * CD + (lane << 2));
    float* dst = agg + (size_t)row * CD + (lane << 2);
    unsafeAtomicAdd(dst + 0, v * b2f(m4.x));
    unsafeAtomicAdd(dst + 1, v * b2f(m4.y));
    unsafeAtomicAdd(dst + 2, v * b2f(m4.z));
    unsafeAtomicAdd(dst + 3, v * b2f(m4.w));
}

// ---------------------------------------------------------------------------
// Kernel 3: out = fp32 elu(agg), vectorized float4.
// ---------------------------------------------------------------------------
__global__ __launch_bounds__(256) void elu_kernel(const float* __restrict__ agg,
                                                  float* __restrict__ out) {
    const size_t i = ((size_t)blockIdx.x * 256 + threadIdx.x) * 4;
    float4 x = *(const float4*)(agg + i);
    float4 o;
    o.x = x.x > 0.f ? x.x : expm1f(x.x);
    o.y = x.y > 0.f ? x.y : expm1f(x.y);
    o.z = x.z > 0.f ? x.z : expm1f(x.z);
    o.w = x.w > 0.f ? x.w : expm1f(x.w);
    *(float4*)(out + i) = o;
}

// ---------------------------------------------------------------------------
// Workspace layout:
//   agg  fp32 [N1*D]           : 204,800,000 B @ offset 0
//   msg  bf16 [N0*D]           :  51,200,000 B @ offset 204,800,000
//   wt   bf16 [D*D]            :     131,072 B @ offset 256,000,000
//   total ~256.2 MB
// ---------------------------------------------------------------------------
extern "C" void kernel_launch(void* const* d_in, const int* in_sizes, int n_in,
                              void* d_out, int out_size, void* d_ws, size_t ws_size,
                              hipStream_t stream) {
    const float* x0   = (const float*)d_in[0];
    // d_in[1] = x_1 : unused by the reference
    const int*   rows = (const int*)d_in[2];
    const int*   cols = (const int*)d_in[3];
    const float* vals = (const float*)d_in[4];
    const float* w    = (const float*)d_in[5];
    float*       out  = (float*)d_out;

    char* ws = (char*)d_ws;
    float*          agg = (float*)ws;
    unsigned short* msg = (unsigned short*)(ws + 204800000);
    unsigned short* wt  = (unsigned short*)(ws + 256000000);

    hipMemsetAsync(agg, 0, (size_t)CN1 * CD * sizeof(float), stream);

    transpose_w<<<CD, CD, 0, stream>>>(w, wt);

    // 100000/16 = 6250 wave-tiles, 4 waves per 256-thread block
    gemm_kernel<<<(6250 + 3) / 4, 256, 0, stream>>>(x0, wt, msg);

    scatter_kernel<<<CNNZ / 4, 256, 0, stream>>>(msg, rows, cols, vals, agg);

    // 200000*256/4 elems per thread / 256 threads = 50000 blocks exactly
    elu_kernel<<<50000, 256, 0, stream>>>(agg, out);
}

// Round 3
// 519.226 us; speedup vs baseline: 3.4369x; 3.4369x over previous
//
#include <hip/hip_runtime.h>
#include <hip/hip_bf16.h>

// Problem constants (from reference setup_inputs)
#define CN0   100000
#define CN1   200000
#define CNNZ  400000
#define CD    256

typedef __attribute__((ext_vector_type(8))) short bfrag8;   // 8 bf16 (4 VGPRs) — MFMA A/B frag
typedef __attribute__((ext_vector_type(4))) float f32x4v;   // MFMA C/D frag

static __device__ __forceinline__ float b2f(unsigned short u) {
    union { unsigned int i; float f; } c; c.i = ((unsigned int)u) << 16; return c.f;
}
static __device__ __forceinline__ unsigned short f2b(float f) {
    union { float f; unsigned int i; } c; c.f = f;
    unsigned int u = c.i;
    unsigned int r = u + 0x7FFFu + ((u >> 16) & 1u);  // round-to-nearest-even
    return (unsigned short)(r >> 16);
}

// ---------------------------------------------------------------------------
// Kernel 0: transpose+convert W fp32 [K=256][N=256] -> Wt bf16 [N][K].
// ---------------------------------------------------------------------------
__global__ __launch_bounds__(256) void transpose_w(const float* __restrict__ w,
                                                   unsigned short* __restrict__ wt) {
    int n = blockIdx.x;   // 0..255
    int k = threadIdx.x;  // 0..255
    wt[n * CD + k] = f2b(w[k * CD + n]);
}

// ---------------------------------------------------------------------------
// Kernel 1: msg[M=100000][256] = bf16(x0) @ bf16(W)  (fp32 accum, bf16 out)
// One wave computes a 16-row x 256-col strip (mfma_f32_16x16x32_bf16).
// ---------------------------------------------------------------------------
__global__ __launch_bounds__(256) void gemm_kernel(const float* __restrict__ x0,
                                                   const unsigned short* __restrict__ wt,
                                                   unsigned short* __restrict__ msg) {
    const int wave = threadIdx.x >> 6;
    const int lane = threadIdx.x & 63;
    const int tile = blockIdx.x * 4 + wave;   // 16-row tile index
    const int m0 = tile * 16;
    if (m0 >= CN0) return;

    const int r16  = lane & 15;
    const int quad = lane >> 4;

    const float* arow = x0 + (size_t)(m0 + r16) * CD + (quad << 3);

    f32x4v acc[16];
#pragma unroll
    for (int i = 0; i < 16; ++i) acc[i] = (f32x4v){0.f, 0.f, 0.f, 0.f};

    for (int k0 = 0; k0 < CD; k0 += 32) {
        float4 a0 = *(const float4*)(arow + k0);
        float4 a1 = *(const float4*)(arow + k0 + 4);
        bfrag8 a;
        a[0] = (short)f2b(a0.x); a[1] = (short)f2b(a0.y);
        a[2] = (short)f2b(a0.z); a[3] = (short)f2b(a0.w);
        a[4] = (short)f2b(a1.x); a[5] = (short)f2b(a1.y);
        a[6] = (short)f2b(a1.z); a[7] = (short)f2b(a1.w);
#pragma unroll
        for (int nt = 0; nt < 16; ++nt) {
            bfrag8 b = *(const bfrag8*)(wt + (size_t)((nt << 4) + r16) * CD + (quad << 3) + k0);
            acc[nt] = __builtin_amdgcn_mfma_f32_16x16x32_bf16(a, b, acc[nt], 0, 0, 0);
        }
    }

    const int mrow = m0 + (quad << 2);
#pragma unroll
    for (int nt = 0; nt < 16; ++nt) {
#pragma unroll
        for (int r = 0; r < 4; ++r) {
            msg[(size_t)(mrow + r) * CD + (nt << 4) + r16] = f2b(acc[nt][r]);
        }
    }
}

// ---------------------------------------------------------------------------
// CSR build: histogram -> 3-kernel exclusive scan -> place
// ---------------------------------------------------------------------------
__global__ __launch_bounds__(256) void hist_kernel(const int* __restrict__ rows,
                                                   int* __restrict__ cnt) {
    int e = blockIdx.x * 256 + threadIdx.x;
    if (e < CNNZ) atomicAdd(&cnt[rows[e]], 1);
}

// scan1: 1024 elements per block (256 threads x 4), exclusive within block
__global__ __launch_bounds__(256) void scan1_kernel(const int* __restrict__ cnt,
                                                    int* __restrict__ offs,
                                                    int* __restrict__ bsum) {
    __shared__ int s[256];
    const int t = threadIdx.x;
    const int base = blockIdx.x * 1024 + t * 4;
    int v0 = (base + 0 < CN1) ? cnt[base + 0] : 0;
    int v1 = (base + 1 < CN1) ? cnt[base + 1] : 0;
    int v2 = (base + 2 < CN1) ? cnt[base + 2] : 0;
    int v3 = (base + 3 < CN1) ? cnt[base + 3] : 0;
    const int mysum = v0 + v1 + v2 + v3;
    s[t] = mysum;
    __syncthreads();
    for (int off = 1; off < 256; off <<= 1) {
        int x = (t >= off) ? s[t - off] : 0;
        __syncthreads();
        s[t] += x;
        __syncthreads();
    }
    int run = s[t] - mysum;   // exclusive prefix of this thread's chunk
    if (base + 0 < CN1) offs[base + 0] = run; run += v0;
    if (base + 1 < CN1) offs[base + 1] = run; run += v1;
    if (base + 2 < CN1) offs[base + 2] = run; run += v2;
    if (base + 3 < CN1) offs[base + 3] = run;
    if (t == 255) bsum[blockIdx.x] = s[255];
}

// scan2: exclusive scan of up to 256 block sums, single block
__global__ __launch_bounds__(256) void scan2_kernel(const int* __restrict__ bsum,
                                                    int* __restrict__ bsum2,
                                                    int nblocks) {
    __shared__ int s[256];
    const int t = threadIdx.x;
    const int v = (t < nblocks) ? bsum[t] : 0;
    s[t] = v;
    __syncthreads();
    for (int off = 1; off < 256; off <<= 1) {
        int x = (t >= off) ? s[t - off] : 0;
        __syncthreads();
        s[t] += x;
        __syncthreads();
    }
    if (t < nblocks) bsum2[t] = s[t] - v;
}

// scan3: add scanned block sums
__global__ __launch_bounds__(256) void scan3_kernel(int* __restrict__ offs,
                                                    const int* __restrict__ bsum2) {
    int i = blockIdx.x * 256 + threadIdx.x;
    if (i < CN1) offs[i] += bsum2[i >> 10];
}

// place edges into CSR order
__global__ __launch_bounds__(256) void place_kernel(const int* __restrict__ rows,
                                                    const int* __restrict__ cols,
                                                    const float* __restrict__ vals,
                                                    const int* __restrict__ offs,
                                                    int* __restrict__ cur,
                                                    int* __restrict__ scol,
                                                    float* __restrict__ sval) {
    int e = blockIdx.x * 256 + threadIdx.x;
    if (e >= CNNZ) return;
    int r = rows[e];
    int pos = offs[r] + atomicAdd(&cur[r], 1);
    scol[pos] = cols[e];
    sval[pos] = vals[e];
}

// ---------------------------------------------------------------------------
// Gather + ELU fused: one wave per output row; lane handles 4 columns.
// out[row][c] = elu( sum_e val_e * msg[col_e][c] )
// ---------------------------------------------------------------------------
__global__ __launch_bounds__(256) void gather_kernel(const unsigned short* __restrict__ msg,
                                                     const int* __restrict__ offs,
                                                     const int* __restrict__ cnt,
                                                     const int* __restrict__ scol,
                                                     const float* __restrict__ sval,
                                                     float* __restrict__ out) {
    const int row = blockIdx.x * 4 + (threadIdx.x >> 6);
    if (row >= CN1) return;
    const int lane = threadIdx.x & 63;

    const int s = offs[row];
    const int n = cnt[row];

    float a0 = 0.f, a1 = 0.f, a2 = 0.f, a3 = 0.f;
    for (int i = s; i < s + n; ++i) {
        const int col = scol[i];
        const float v = sval[i];
        const ushort4 m = *(const ushort4*)(msg + (size_t)col * CD + (lane << 2));
        a0 += v * b2f(m.x);
        a1 += v * b2f(m.y);
        a2 += v * b2f(m.z);
        a3 += v * b2f(m.w);
    }
    float4 o;
    o.x = a0 > 0.f ? a0 : expm1f(a0);
    o.y = a1 > 0.f ? a1 : expm1f(a1);
    o.z = a2 > 0.f ? a2 : expm1f(a2);
    o.w = a3 > 0.f ? a3 : expm1f(a3);
    *(float4*)(out + (size_t)row * CD + (lane << 2)) = o;
}

// ---------------------------------------------------------------------------
// Workspace layout (bytes):
//   msg   bf16 [N0*CD]  @          0   (51,200,000)
//   wt    bf16 [CD*CD]  @ 51,200,000   (   131,072)
//   cnt   int  [N1]     @ 51,331,072   (   800,000)   \ one contiguous
//   cur   int  [N1]     @ 52,131,072   (   800,000)   / 1.6 MB memset
//   offs  int  [N1]     @ 52,931,072   (   800,000)
//   bsum  int  [256]    @ 53,731,072   (     1,024)
//   bsum2 int  [256]    @ 53,732,096   (     1,024)
//   scol  int  [NNZ]    @ 53,733,120   ( 1,600,000)
//   sval  f32  [NNZ]    @ 55,333,120   ( 1,600,000)
//   total ~56.9 MB
// ---------------------------------------------------------------------------
extern "C" void kernel_launch(void* const* d_in, const int* in_sizes, int n_in,
                              void* d_out, int out_size, void* d_ws, size_t ws_size,
                              hipStream_t stream) {
    const float* x0   = (const float*)d_in[0];
    // d_in[1] = x_1 : unused by the reference
    const int*   rows = (const int*)d_in[2];
    const int*   cols = (const int*)d_in[3];
    const float* vals = (const float*)d_in[4];
    const float* w    = (const float*)d_in[5];
    float*       out  = (float*)d_out;

    char* ws = (char*)d_ws;
    unsigned short* msg   = (unsigned short*)(ws);
    unsigned short* wt    = (unsigned short*)(ws + 51200000);
    int*            cnt   = (int*)(ws + 51331072);
    int*            cur   = (int*)(ws + 52131072);
    int*            offs  = (int*)(ws + 52931072);
    int*            bsum  = (int*)(ws + 53731072);
    int*            bsum2 = (int*)(ws + 53732096);
    int*            scol  = (int*)(ws + 53733120);
    float*          sval  = (float*)(ws + 55333120);

    // zero cnt + cur (contiguous)
    hipMemsetAsync(cnt, 0, 2 * CN1 * sizeof(int), stream);

    transpose_w<<<CD, CD, 0, stream>>>(w, wt);

    gemm_kernel<<<(6250 + 3) / 4, 256, 0, stream>>>(x0, wt, msg);

    // CSR build
    hist_kernel<<<(CNNZ + 255) / 256, 256, 0, stream>>>(rows, cnt);
    const int nblk = (CN1 + 1023) / 1024;   // 196
    scan1_kernel<<<nblk, 256, 0, stream>>>(cnt, offs, bsum);
    scan2_kernel<<<1, 256, 0, stream>>>(bsum, bsum2, nblk);
    scan3_kernel<<<(CN1 + 255) / 256, 256, 0, stream>>>(offs, bsum2);
    place_kernel<<<(CNNZ + 255) / 256, 256, 0, stream>>>(rows, cols, vals, offs, cur, scol, sval);

    // fused gather + ELU -> out
    gather_kernel<<<(CN1 + 3) / 4, 256, 0, stream>>>(msg, offs, cnt, scol, sval, out);
}

// Round 4
// 472.776 us; speedup vs baseline: 3.7746x; 1.0983x over previous
//
#include <hip/hip_runtime.h>
#include <hip/hip_bf16.h>

// Problem constants (from reference setup_inputs)
#define CN0   100000
#define CN1   200000
#define CNNZ  400000
#define CD    256

typedef __attribute__((ext_vector_type(8))) short bfrag8;   // 8 bf16 (4 VGPRs) — MFMA A/B frag
typedef __attribute__((ext_vector_type(4))) float f32x4v;   // MFMA C/D frag

static __device__ __forceinline__ float b2f(unsigned short u) {
    union { unsigned int i; float f; } c; c.i = ((unsigned int)u) << 16; return c.f;
}
static __device__ __forceinline__ unsigned short f2b(float f) {
    union { float f; unsigned int i; } c; c.f = f;
    unsigned int u = c.i;
    unsigned int r = u + 0x7FFFu + ((u >> 16) & 1u);  // round-to-nearest-even
    return (unsigned short)(r >> 16);
}

// ---------------------------------------------------------------------------
// Kernel 0: transpose+convert W fp32 [K=256][N=256] -> Wt bf16 [N][K].
// ---------------------------------------------------------------------------
__global__ __launch_bounds__(256) void transpose_w(const float* __restrict__ w,
                                                   unsigned short* __restrict__ wt) {
    int n = blockIdx.x;   // 0..255
    int k = threadIdx.x;  // 0..255
    wt[n * CD + k] = f2b(w[k * CD + n]);
}

// ---------------------------------------------------------------------------
// Kernel 1: msg = bf16(x0) @ bf16(W), fp32 accum, bf16 out.
// Block = 64 rows x 256 cols; each wave = 64 rows x 64 cols (4x4 acc frags).
// Waves split N, so all 4 waves load the SAME A rows -> L1 hits for 3 of 4.
// Explicit software pipeline: k-step k+1 loads issue before k's convert+MFMA.
//   A frag: lane holds A[m][k0 + quad*8 + j]       (32B fp32 -> 8 bf16)
//   B frag: lane holds Wt[n = base+r16][k0+quad*8..] (16B contig)
//   C/D:    col = lane&15 (n), row = quad*4 + reg   (m)
// ---------------------------------------------------------------------------
__global__ __launch_bounds__(256) void gemm_kernel(const float* __restrict__ x0,
                                                   const unsigned short* __restrict__ wt,
                                                   unsigned short* __restrict__ msg) {
    const int wave = threadIdx.x >> 6;
    const int lane = threadIdx.x & 63;
    const int r16  = lane & 15;
    const int quad = lane >> 4;

    const int m0 = blockIdx.x * 64;     // block row base
    const int nb = wave * 64;           // wave col base

    const float* arow[4];
#pragma unroll
    for (int mt = 0; mt < 4; ++mt) {
        int m = m0 + mt * 16 + r16;
        if (m >= CN0) m = CN0 - 1;      // clamp OOB lanes; stores are guarded
        arow[mt] = x0 + (size_t)m * CD + (quad << 3);
    }
    const unsigned short* brow[4];
#pragma unroll
    for (int nt = 0; nt < 4; ++nt)
        brow[nt] = wt + (size_t)(nb + nt * 16 + r16) * CD + (quad << 3);

    f32x4v acc[4][4];
#pragma unroll
    for (int mt = 0; mt < 4; ++mt)
#pragma unroll
        for (int nt = 0; nt < 4; ++nt) acc[mt][nt] = (f32x4v){0.f, 0.f, 0.f, 0.f};

    // ---- prefetch k-step 0 ----
    float4 Ar0[4], Ar1[4];
    bfrag8 Bf[4];
#pragma unroll
    for (int mt = 0; mt < 4; ++mt) {
        Ar0[mt] = *(const float4*)(arow[mt]);
        Ar1[mt] = *(const float4*)(arow[mt] + 4);
    }
#pragma unroll
    for (int nt = 0; nt < 4; ++nt) Bf[nt] = *(const bfrag8*)(brow[nt]);

#pragma unroll
    for (int k0 = 0; k0 < 8; ++k0) {
        // capture current
        float4 a0c[4], a1c[4];
        bfrag8 bc[4];
#pragma unroll
        for (int mt = 0; mt < 4; ++mt) { a0c[mt] = Ar0[mt]; a1c[mt] = Ar1[mt]; }
#pragma unroll
        for (int nt = 0; nt < 4; ++nt) bc[nt] = Bf[nt];

        // issue next k-step's loads (independent of current compute)
        if (k0 < 7) {
            const int ko = (k0 + 1) * 32;
#pragma unroll
            for (int mt = 0; mt < 4; ++mt) {
                Ar0[mt] = *(const float4*)(arow[mt] + ko);
                Ar1[mt] = *(const float4*)(arow[mt] + ko + 4);
            }
#pragma unroll
            for (int nt = 0; nt < 4; ++nt) Bf[nt] = *(const bfrag8*)(brow[nt] + ko);
        }

        // convert A to bf16 frags and MFMA
        bfrag8 af[4];
#pragma unroll
        for (int mt = 0; mt < 4; ++mt) {
            af[mt][0] = (short)f2b(a0c[mt].x); af[mt][1] = (short)f2b(a0c[mt].y);
            af[mt][2] = (short)f2b(a0c[mt].z); af[mt][3] = (short)f2b(a0c[mt].w);
            af[mt][4] = (short)f2b(a1c[mt].x); af[mt][5] = (short)f2b(a1c[mt].y);
            af[mt][6] = (short)f2b(a1c[mt].z); af[mt][7] = (short)f2b(a1c[mt].w);
        }
#pragma unroll
        for (int mt = 0; mt < 4; ++mt)
#pragma unroll
            for (int nt = 0; nt < 4; ++nt)
                acc[mt][nt] = __builtin_amdgcn_mfma_f32_16x16x32_bf16(af[mt], bc[nt], acc[mt][nt], 0, 0, 0);
    }

    // ---- store: row = m0 + mt*16 + quad*4 + r, col = nb + nt*16 + r16 ----
#pragma unroll
    for (int mt = 0; mt < 4; ++mt) {
#pragma unroll
        for (int r = 0; r < 4; ++r) {
            const int m = m0 + mt * 16 + (quad << 2) + r;
            if (m < CN0) {
#pragma unroll
                for (int nt = 0; nt < 4; ++nt)
                    msg[(size_t)m * CD + nb + (nt << 4) + r16] = f2b(acc[mt][nt][r]);
            }
        }
    }
}

// ---------------------------------------------------------------------------
// CSR build: histogram -> 2-kernel exclusive scan (block sums folded into
// consumers) -> place
// ---------------------------------------------------------------------------
__global__ __launch_bounds__(256) void hist_kernel(const int* __restrict__ rows,
                                                   int* __restrict__ cnt) {
    int e = blockIdx.x * 256 + threadIdx.x;
    if (e < CNNZ) atomicAdd(&cnt[rows[e]], 1);
}

// scan1: 1024 elements per block (256 threads x 4), exclusive within block
__global__ __launch_bounds__(256) void scan1_kernel(const int* __restrict__ cnt,
                                                    int* __restrict__ offs,
                                                    int* __restrict__ bsum) {
    __shared__ int s[256];
    const int t = threadIdx.x;
    const int base = blockIdx.x * 1024 + t * 4;
    int v0 = (base + 0 < CN1) ? cnt[base + 0] : 0;
    int v1 = (base + 1 < CN1) ? cnt[base + 1] : 0;
    int v2 = (base + 2 < CN1) ? cnt[base + 2] : 0;
    int v3 = (base + 3 < CN1) ? cnt[base + 3] : 0;
    const int mysum = v0 + v1 + v2 + v3;
    s[t] = mysum;
    __syncthreads();
    for (int off = 1; off < 256; off <<= 1) {
        int x = (t >= off) ? s[t - off] : 0;
        __syncthreads();
        s[t] += x;
        __syncthreads();
    }
    int run = s[t] - mysum;   // exclusive prefix of this thread's chunk
    if (base + 0 < CN1) offs[base + 0] = run; run += v0;
    if (base + 1 < CN1) offs[base + 1] = run; run += v1;
    if (base + 2 < CN1) offs[base + 2] = run; run += v2;
    if (base + 3 < CN1) offs[base + 3] = run;
    if (t == 255) bsum[blockIdx.x] = s[255];
}

// scan2: exclusive scan of up to 256 block sums, single block
__global__ __launch_bounds__(256) void scan2_kernel(const int* __restrict__ bsum,
                                                    int* __restrict__ bsum2,
                                                    int nblocks) {
    __shared__ int s[256];
    const int t = threadIdx.x;
    const int v = (t < nblocks) ? bsum[t] : 0;
    s[t] = v;
    __syncthreads();
    for (int off = 1; off < 256; off <<= 1) {
        int x = (t >= off) ? s[t - off] : 0;
        __syncthreads();
        s[t] += x;
        __syncthreads();
    }
    if (t < nblocks) bsum2[t] = s[t] - v;
}

// place edges into CSR order (block-sum add folded in)
__global__ __launch_bounds__(256) void place_kernel(const int* __restrict__ rows,
                                                    const int* __restrict__ cols,
                                                    const float* __restrict__ vals,
                                                    const int* __restrict__ offs,
                                                    const int* __restrict__ bsum2,
                                                    int* __restrict__ cur,
                                                    int* __restrict__ scol,
                                                    float* __restrict__ sval) {
    int e = blockIdx.x * 256 + threadIdx.x;
    if (e >= CNNZ) return;
    int r = rows[e];
    int pos = offs[r] + bsum2[r >> 10] + atomicAdd(&cur[r], 1);
    scol[pos] = cols[e];
    sval[pos] = vals[e];
}

// ---------------------------------------------------------------------------
// Gather + ELU fused: one wave per output row; lane handles 4 columns.
// out[row][c] = elu( sum_e val_e * msg[col_e][c] )
// ---------------------------------------------------------------------------
__global__ __launch_bounds__(256) void gather_kernel(const unsigned short* __restrict__ msg,
                                                     const int* __restrict__ offs,
                                                     const int* __restrict__ bsum2,
                                                     const int* __restrict__ cnt,
                                                     const int* __restrict__ scol,
                                                     const float* __restrict__ sval,
                                                     float* __restrict__ out) {
    const int row = blockIdx.x * 4 + (threadIdx.x >> 6);
    if (row >= CN1) return;
    const int lane = threadIdx.x & 63;

    const int s = offs[row] + bsum2[row >> 10];
    const int n = cnt[row];

    float a0 = 0.f, a1 = 0.f, a2 = 0.f, a3 = 0.f;
    for (int i = s; i < s + n; ++i) {
        const int col = scol[i];
        const float v = sval[i];
        const ushort4 m = *(const ushort4*)(msg + (size_t)col * CD + (lane << 2));
        a0 += v * b2f(m.x);
        a1 += v * b2f(m.y);
        a2 += v * b2f(m.z);
        a3 += v * b2f(m.w);
    }
    float4 o;
    o.x = a0 > 0.f ? a0 : expm1f(a0);
    o.y = a1 > 0.f ? a1 : expm1f(a1);
    o.z = a2 > 0.f ? a2 : expm1f(a2);
    o.w = a3 > 0.f ? a3 : expm1f(a3);
    *(float4*)(out + (size_t)row * CD + (lane << 2)) = o;
}

// ---------------------------------------------------------------------------
// Workspace layout (bytes):
//   msg   bf16 [N0*CD]  @          0   (51,200,000)
//   wt    bf16 [CD*CD]  @ 51,200,000   (   131,072)
//   cnt   int  [N1]     @ 51,331,072   (   800,000)   \ one contiguous
//   cur   int  [N1]     @ 52,131,072   (   800,000)   / 1.6 MB memset
//   offs  int  [N1]     @ 52,931,072   (   800,000)
//   bsum  int  [256]    @ 53,731,072   (     1,024)
//   bsum2 int  [256]    @ 53,732,096   (     1,024)
//   scol  int  [NNZ]    @ 53,733,120   ( 1,600,000)
//   sval  f32  [NNZ]    @ 55,333,120   ( 1,600,000)
//   total ~56.9 MB
// ---------------------------------------------------------------------------
extern "C" void kernel_launch(void* const* d_in, const int* in_sizes, int n_in,
                              void* d_out, int out_size, void* d_ws, size_t ws_size,
                              hipStream_t stream) {
    const float* x0   = (const float*)d_in[0];
    // d_in[1] = x_1 : unused by the reference
    const int*   rows = (const int*)d_in[2];
    const int*   cols = (const int*)d_in[3];
    const float* vals = (const float*)d_in[4];
    const float* w    = (const float*)d_in[5];
    float*       out  = (float*)d_out;

    char* ws = (char*)d_ws;
    unsigned short* msg   = (unsigned short*)(ws);
    unsigned short* wt    = (unsigned short*)(ws + 51200000);
    int*            cnt   = (int*)(ws + 51331072);
    int*            cur   = (int*)(ws + 52131072);
    int*            offs  = (int*)(ws + 52931072);
    int*            bsum  = (int*)(ws + 53731072);
    int*            bsum2 = (int*)(ws + 53732096);
    int*            scol  = (int*)(ws + 53733120);
    float*          sval  = (float*)(ws + 55333120);

    // zero cnt + cur (contiguous)
    hipMemsetAsync(cnt, 0, 2 * CN1 * sizeof(int), stream);

    transpose_w<<<CD, CD, 0, stream>>>(w, wt);

    // 64 rows per block -> 1563 blocks
    gemm_kernel<<<(CN0 + 63) / 64, 256, 0, stream>>>(x0, wt, msg);

    // CSR build
    hist_kernel<<<(CNNZ + 255) / 256, 256, 0, stream>>>(rows, cnt);
    const int nblk = (CN1 + 1023) / 1024;   // 196
    scan1_kernel<<<nblk, 256, 0, stream>>>(cnt, offs, bsum);
    scan2_kernel<<<1, 256, 0, stream>>>(bsum, bsum2, nblk);
    place_kernel<<<(CNNZ + 255) / 256, 256, 0, stream>>>(rows, cols, vals, offs, bsum2, cur, scol, sval);

    // fused gather + ELU -> out
    gather_kernel<<<(CN1 + 3) / 4, 256, 0, stream>>>(msg, offs, bsum2, cnt, scol, sval, out);
}